// Round 3
// baseline (331.471 us; speedup 1.0000x reference)
//
#include <hip/hip_runtime.h>
#include <stdint.h>

// out[M,N] = x[M,K] @ dequant(W_q_packed)[K,N] + bias[N]
// M=N=K=4096, 4-bit nibbles packed 8/int32 along K, GROUP=128.
// ws: xb (bf16 x, 32MB) + wt (bf16 W^T N-major, 32MB); bf16 MFMA GEMM.
// R3: double-buffered LDS, ONE barrier per K-iter, next tile's
// global_load_lds issued right after the barrier -> staging latency gets a
// full compute phase in flight before the next barrier's vmcnt drain.

#define M_DIM 4096
#define N_DIM 4096
#define K_DIM 4096

typedef __attribute__((ext_vector_type(8))) short short8;
typedef __attribute__((ext_vector_type(4))) float f32x4;

__device__ __forceinline__ unsigned short f2bf(float f) {
  uint32_t u = __builtin_bit_cast(uint32_t, f);
  u += 0x7fffu + ((u >> 16) & 1u);   // round-to-nearest-even
  return (unsigned short)(u >> 16);
}

// ---------- kernel 1: x fp32 -> bf16 ----------
__global__ __launch_bounds__(256) void cvt_x_kernel(const float* __restrict__ x,
                                                    unsigned short* __restrict__ xb) {
  const int total = (M_DIM * K_DIM) / 4;
  const float4* x4 = (const float4*)x;
  ushort4* o4 = (ushort4*)xb;
  for (int i = blockIdx.x * 256 + threadIdx.x; i < total; i += gridDim.x * 256) {
    float4 v = x4[i];
    ushort4 o;
    o.x = f2bf(v.x); o.y = f2bf(v.y); o.z = f2bf(v.z); o.w = f2bf(v.w);
    o4[i] = o;
  }
}

// ---------- kernel 2: dequant + transpose -> W^T (N x K) bf16 ----------
__global__ __launch_bounds__(256) void dequant_kernel(const int* __restrict__ Wq,
                                                      const float* __restrict__ scales,
                                                      const float* __restrict__ zeros,
                                                      unsigned short* __restrict__ wt) {
  __shared__ uint4 Ts[32 * 64];  // 32 KB
  const int tid = threadIdx.x;
  const int n0 = blockIdx.x * 32;
  const int gk0 = blockIdx.y * 64;

#pragma unroll
  for (int p = 0; p < 8; ++p) {
    int e = p * 256 + tid;
    int n_l = e & 31;
    int gk_l = e >> 5;
    int gk = gk0 + gk_l;
    int n = n0 + n_l;
    int g = gk >> 4;                // group = (gk*8)/128
    uint32_t q = (uint32_t)Wq[gk * N_DIM + n];
    float s = scales[g * N_DIM + n];
    float z = zeros[g * N_DIM + n];
    unsigned short b[8];
#pragma unroll
    for (int j = 0; j < 8; ++j) {
      float f = ((float)((q >> (4 * j)) & 15u) - z) * s;
      b[j] = f2bf(f);
    }
    uint4 cell;
    cell.x = (uint32_t)b[0] | ((uint32_t)b[1] << 16);
    cell.y = (uint32_t)b[2] | ((uint32_t)b[3] << 16);
    cell.z = (uint32_t)b[4] | ((uint32_t)b[5] << 16);
    cell.w = (uint32_t)b[6] | ((uint32_t)b[7] << 16);
    Ts[n_l * 64 + (gk_l ^ (n_l & 7))] = cell;
  }
  __syncthreads();
  uint4* dst = (uint4*)wt;
#pragma unroll
  for (int p = 0; p < 8; ++p) {
    int n_l = p * 4 + (tid >> 6);
    int gk_l = tid & 63;
    uint4 cell = Ts[n_l * 64 + (gk_l ^ (n_l & 7))];
    dst[(size_t)(n0 + n_l) * (K_DIM / 8) + (gk0 + gk_l)] = cell;
  }
}

// ---------- kernel 3: bf16 GEMM, C = A @ Bt^T + bias ----------
// 128x128 tile, 4 waves 2x2, each wave 64x64 via 4x4 of 16x16x32 MFMA, BK=32.
// LDS: 16B cells, cell(row,kc) = row*4 + (kc ^ ((row>>1)&3)) -> staging
// 64B-coalesced, fragment ds_read_b128 2-way-free. Double-buffered.
__global__ __launch_bounds__(256) void gemm_bt_kernel(const unsigned short* __restrict__ A,
                                                      const unsigned short* __restrict__ Bt,
                                                      const float* __restrict__ bias,
                                                      float* __restrict__ C) {
  __shared__ short8 As[2][512];  // 16 KB
  __shared__ short8 Bs[2][512];  // 16 KB
  const int tid = threadIdx.x;
  const int lane = tid & 63;
  const int w = tid >> 6;
  const int wm = w >> 1, wn = w & 1;
  const int m0 = blockIdx.y * 128;
  const int n0 = blockIdx.x * 128;

  // staging: two 64-cell windows per wave
  const int c0 = w * 128 + lane;
  const int c1 = c0 + 64;
  const int r0 = c0 >> 2, kc0 = (c0 & 3) ^ ((r0 >> 1) & 3);
  const int r1 = c1 >> 2, kc1 = (c1 & 3) ^ ((r1 >> 1) & 3);
  const unsigned short* ap0 = A + (size_t)(m0 + r0) * K_DIM + kc0 * 8;
  const unsigned short* ap1 = A + (size_t)(m0 + r1) * K_DIM + kc1 * 8;
  const unsigned short* bp0 = Bt + (size_t)(n0 + r0) * K_DIM + kc0 * 8;
  const unsigned short* bp1 = Bt + (size_t)(n0 + r1) * K_DIM + kc1 * 8;

  f32x4 acc[4][4] = {};

  const int fr = lane & 15;   // m (A) / n (B) within 16-tile
  const int fc = lane >> 4;   // k-chunk 0..3
  const int swz = fc ^ ((fr >> 1) & 3);
  const int a_base = (wm * 64 + fr) * 4 + swz;   // + mi*64
  const int b_base = (wn * 64 + fr) * 4 + swz;   // + ni*64

#define ISSUE(t, buf)                                                          \
  do {                                                                         \
    const int _k = (t) * 32;                                                   \
    __builtin_amdgcn_global_load_lds(                                          \
        (const __attribute__((address_space(1))) void*)(ap0 + _k),             \
        (__attribute__((address_space(3))) void*)&As[buf][c0], 16, 0, 0);      \
    __builtin_amdgcn_global_load_lds(                                          \
        (const __attribute__((address_space(1))) void*)(bp0 + _k),             \
        (__attribute__((address_space(3))) void*)&Bs[buf][c0], 16, 0, 0);      \
    __builtin_amdgcn_global_load_lds(                                          \
        (const __attribute__((address_space(1))) void*)(ap1 + _k),             \
        (__attribute__((address_space(3))) void*)&As[buf][c1], 16, 0, 0);      \
    __builtin_amdgcn_global_load_lds(                                          \
        (const __attribute__((address_space(1))) void*)(bp1 + _k),             \
        (__attribute__((address_space(3))) void*)&Bs[buf][c1], 16, 0, 0);      \
  } while (0)

#define COMPUTE(buf)                                                           \
  do {                                                                         \
    short8 af[4], bv[4];                                                       \
    _Pragma("unroll") for (int mi = 0; mi < 4; ++mi)                           \
        af[mi] = As[buf][a_base + mi * 64];                                    \
    _Pragma("unroll") for (int ni = 0; ni < 4; ++ni)                           \
        bv[ni] = Bs[buf][b_base + ni * 64];                                    \
    _Pragma("unroll") for (int mi = 0; mi < 4; ++mi)                           \
        _Pragma("unroll") for (int ni = 0; ni < 4; ++ni)                       \
            acc[mi][ni] = __builtin_amdgcn_mfma_f32_16x16x32_bf16(             \
                af[mi], bv[ni], acc[mi][ni], 0, 0, 0);                         \
  } while (0)

  ISSUE(0, 0);
  const int NK = K_DIM / 32;      // 128
  for (int kk = 0; kk < NK - 2; kk += 2) {
    __syncthreads();              // drains tile kk (buf0)
    ISSUE(kk + 1, 1);
    COMPUTE(0);
    __syncthreads();              // drains tile kk+1 (buf1)
    ISSUE(kk + 2, 0);
    COMPUTE(1);
  }
  // tail: tiles NK-2 (buf0, already issued), NK-1
  __syncthreads();
  ISSUE(NK - 1, 1);
  COMPUTE(0);
  __syncthreads();
  COMPUTE(1);

#undef ISSUE
#undef COMPUTE

  // epilogue: C/D layout col=lane&15, row=(lane>>4)*4+reg
  const int rr = (lane >> 4) * 4;
#pragma unroll
  for (int ni = 0; ni < 4; ++ni) {
    const int gn = n0 + wn * 64 + ni * 16 + fr;
    const float bvv = bias[gn];
#pragma unroll
    for (int mi = 0; mi < 4; ++mi) {
      const int gm = m0 + wm * 64 + mi * 16 + rr;
#pragma unroll
      for (int r = 0; r < 4; ++r)
        C[(size_t)(gm + r) * N_DIM + gn] = acc[mi][ni][r] + bvv;
    }
  }
}

extern "C" void kernel_launch(void* const* d_in, const int* in_sizes, int n_in,
                              void* d_out, int out_size, void* d_ws, size_t ws_size,
                              hipStream_t stream) {
  const float* x = (const float*)d_in[0];
  const int* wq = (const int*)d_in[1];
  const float* sc = (const float*)d_in[2];
  const float* zr = (const float*)d_in[3];
  const float* bias = (const float*)d_in[4];
  float* out = (float*)d_out;

  unsigned short* xb = (unsigned short*)d_ws;
  unsigned short* wt = (unsigned short*)((char*)d_ws + (size_t)M_DIM * K_DIM * 2);

  cvt_x_kernel<<<dim3(2048), dim3(256), 0, stream>>>(x, xb);
  dequant_kernel<<<dim3(N_DIM / 32, (K_DIM / 8) / 64), dim3(256), 0, stream>>>(wq, sc, zr, wt);
  gemm_bt_kernel<<<dim3(N_DIM / 128, M_DIM / 128), dim3(256), 0, stream>>>(xb, wt, bias, out);
}

// Round 4
// 288.431 us; speedup vs baseline: 1.1492x; 1.1492x over previous
//
#include <hip/hip_runtime.h>
#include <stdint.h>

// out[M,N] = x[M,K] @ dequant(W_q_packed)[K,N] + bias[N]
// M=N=K=4096, 4-bit nibbles packed 8/int32 along K, GROUP=128.
// ws: xb (bf16 x, 32MB) + wt (bf16 W^T N-major, 32MB); bf16 MFMA GEMM.
// R4: revert dbuf (regressed, m99-style). BK=64: half the barrier/drain
// events. LDS cell(row,kc) = row*8 + (kc^(row&7)): staging coalesced at
// 128B/row, fragment ds_read_b128 uniform over all 8 bank-quads (free).

#define M_DIM 4096
#define N_DIM 4096
#define K_DIM 4096

typedef __attribute__((ext_vector_type(8))) short short8;
typedef __attribute__((ext_vector_type(4))) float f32x4;

__device__ __forceinline__ unsigned short f2bf(float f) {
  uint32_t u = __builtin_bit_cast(uint32_t, f);
  u += 0x7fffu + ((u >> 16) & 1u);   // round-to-nearest-even
  return (unsigned short)(u >> 16);
}

// ---------- kernel 1: x fp32 -> bf16 ----------
__global__ __launch_bounds__(256) void cvt_x_kernel(const float* __restrict__ x,
                                                    unsigned short* __restrict__ xb) {
  const int total = (M_DIM * K_DIM) / 4;
  const float4* x4 = (const float4*)x;
  ushort4* o4 = (ushort4*)xb;
  for (int i = blockIdx.x * 256 + threadIdx.x; i < total; i += gridDim.x * 256) {
    float4 v = x4[i];
    ushort4 o;
    o.x = f2bf(v.x); o.y = f2bf(v.y); o.z = f2bf(v.z); o.w = f2bf(v.w);
    o4[i] = o;
  }
}

// ---------- kernel 2: dequant + transpose -> W^T (N x K) bf16 ----------
__global__ __launch_bounds__(256) void dequant_kernel(const int* __restrict__ Wq,
                                                      const float* __restrict__ scales,
                                                      const float* __restrict__ zeros,
                                                      unsigned short* __restrict__ wt) {
  __shared__ uint4 Ts[32 * 64];  // 32 KB
  const int tid = threadIdx.x;
  const int n0 = blockIdx.x * 32;
  const int gk0 = blockIdx.y * 64;

#pragma unroll
  for (int p = 0; p < 8; ++p) {
    int e = p * 256 + tid;
    int n_l = e & 31;
    int gk_l = e >> 5;
    int gk = gk0 + gk_l;
    int n = n0 + n_l;
    int g = gk >> 4;                // group = (gk*8)/128
    uint32_t q = (uint32_t)Wq[gk * N_DIM + n];
    float s = scales[g * N_DIM + n];
    float z = zeros[g * N_DIM + n];
    unsigned short b[8];
#pragma unroll
    for (int j = 0; j < 8; ++j) {
      float f = ((float)((q >> (4 * j)) & 15u) - z) * s;
      b[j] = f2bf(f);
    }
    uint4 cell;
    cell.x = (uint32_t)b[0] | ((uint32_t)b[1] << 16);
    cell.y = (uint32_t)b[2] | ((uint32_t)b[3] << 16);
    cell.z = (uint32_t)b[4] | ((uint32_t)b[5] << 16);
    cell.w = (uint32_t)b[6] | ((uint32_t)b[7] << 16);
    Ts[n_l * 64 + (gk_l ^ (n_l & 7))] = cell;
  }
  __syncthreads();
  uint4* dst = (uint4*)wt;
#pragma unroll
  for (int p = 0; p < 8; ++p) {
    int n_l = p * 4 + (tid >> 6);
    int gk_l = tid & 63;
    uint4 cell = Ts[n_l * 64 + (gk_l ^ (n_l & 7))];
    dst[(size_t)(n0 + n_l) * (K_DIM / 8) + (gk0 + gk_l)] = cell;
  }
}

// ---------- kernel 3: bf16 GEMM, C = A @ Bt^T + bias ----------
// 128x128 tile, 4 waves 2x2, each wave 64x64 via 4x4 of 16x16x32 MFMA, BK=64.
// LDS: 16B cells, tile = 128 rows x 8 k-chunks, cell = row*8 + (kc^(row&7)).
//  - staging: each 8-lane group covers one row's contiguous 128 B;
//  - windows j=0..3 differ by uniform 8-row stride -> one varying offset;
//  - fragment read k-step s: index (row)*8 + ((s*4+fc)^(fr&7)) -> each
//    bank-quad hit exactly 4x per wave = conflict-free for b128.
__global__ __launch_bounds__(256) void gemm_bt_kernel(const unsigned short* __restrict__ A,
                                                      const unsigned short* __restrict__ Bt,
                                                      const float* __restrict__ bias,
                                                      float* __restrict__ C) {
  __shared__ short8 As[1024];  // 16 KB
  __shared__ short8 Bs[1024];  // 16 KB
  const int tid = threadIdx.x;
  const int lane = tid & 63;
  const int w = tid >> 6;
  const int wm = w >> 1, wn = w & 1;
  const int m0 = blockIdx.y * 128;
  const int n0 = blockIdx.x * 128;

  // staging: window j covers cells [w*256 + j*64, +64); lane -> cell c0 + j*64
  const int c0 = w * 256 + lane;
  const int row0 = c0 >> 3;              // rows row0 + 8j
  const int kcx0 = c0 & 7;
  const int kc0 = kcx0 ^ (row0 & 7);     // invariant across j (row step 8)
  const unsigned short* Ablk = A + (size_t)m0 * K_DIM;
  const unsigned short* Bblk = Bt + (size_t)n0 * K_DIM;
  const int voff = row0 * K_DIM + kc0 * 8;   // varying elem offset, +8*K per j

  f32x4 acc[4][4] = {};

  const int fr = lane & 15;   // m (A) / n (B) within 16-tile
  const int fc = lane >> 4;   // k-quarter 0..3
  // k-step s: cell = (row)*8 + ((s*4+fc)^(fr&7)); row = w?*64 + mi*16 + fr
  const int a_row8 = (wm * 64 + fr) * 8;
  const int b_row8 = (wn * 64 + fr) * 8;
  const int kx0 = fc ^ (fr & 7);          // s=0
  const int kx1 = (4 + fc) ^ (fr & 7);    // s=1

  for (int kk = 0; kk < K_DIM / 64; ++kk) {
    const int k0 = kk * 64;
    __syncthreads();
#pragma unroll
    for (int j = 0; j < 4; ++j) {
      __builtin_amdgcn_global_load_lds(
          (const __attribute__((address_space(1))) void*)(Ablk + voff + j * 8 * K_DIM + k0),
          (__attribute__((address_space(3))) void*)&As[c0 + j * 64], 16, 0, 0);
      __builtin_amdgcn_global_load_lds(
          (const __attribute__((address_space(1))) void*)(Bblk + voff + j * 8 * K_DIM + k0),
          (__attribute__((address_space(3))) void*)&Bs[c0 + j * 64], 16, 0, 0);
    }
    __syncthreads();

    {
      short8 af[4], bv[4];
#pragma unroll
      for (int mi = 0; mi < 4; ++mi) af[mi] = As[a_row8 + mi * 128 + kx0];
#pragma unroll
      for (int ni = 0; ni < 4; ++ni) bv[ni] = Bs[b_row8 + ni * 128 + kx0];
#pragma unroll
      for (int mi = 0; mi < 4; ++mi)
#pragma unroll
        for (int ni = 0; ni < 4; ++ni)
          acc[mi][ni] = __builtin_amdgcn_mfma_f32_16x16x32_bf16(af[mi], bv[ni], acc[mi][ni], 0, 0, 0);
    }
    {
      short8 af[4], bv[4];
#pragma unroll
      for (int mi = 0; mi < 4; ++mi) af[mi] = As[a_row8 + mi * 128 + kx1];
#pragma unroll
      for (int ni = 0; ni < 4; ++ni) bv[ni] = Bs[b_row8 + ni * 128 + kx1];
#pragma unroll
      for (int mi = 0; mi < 4; ++mi)
#pragma unroll
        for (int ni = 0; ni < 4; ++ni)
          acc[mi][ni] = __builtin_amdgcn_mfma_f32_16x16x32_bf16(af[mi], bv[ni], acc[mi][ni], 0, 0, 0);
    }
  }

  // epilogue: C/D layout col=lane&15, row=(lane>>4)*4+reg
  const int rr = (lane >> 4) * 4;
#pragma unroll
  for (int ni = 0; ni < 4; ++ni) {
    const int gn = n0 + wn * 64 + ni * 16 + fr;
    const float bvv = bias[gn];
#pragma unroll
    for (int mi = 0; mi < 4; ++mi) {
      const int gm = m0 + wm * 64 + mi * 16 + rr;
#pragma unroll
      for (int r = 0; r < 4; ++r)
        C[(size_t)(gm + r) * N_DIM + gn] = acc[mi][ni][r] + bvv;
    }
  }
}

extern "C" void kernel_launch(void* const* d_in, const int* in_sizes, int n_in,
                              void* d_out, int out_size, void* d_ws, size_t ws_size,
                              hipStream_t stream) {
  const float* x = (const float*)d_in[0];
  const int* wq = (const int*)d_in[1];
  const float* sc = (const float*)d_in[2];
  const float* zr = (const float*)d_in[3];
  const float* bias = (const float*)d_in[4];
  float* out = (float*)d_out;

  unsigned short* xb = (unsigned short*)d_ws;
  unsigned short* wt = (unsigned short*)((char*)d_ws + (size_t)M_DIM * K_DIM * 2);

  cvt_x_kernel<<<dim3(2048), dim3(256), 0, stream>>>(x, xb);
  dequant_kernel<<<dim3(N_DIM / 32, (K_DIM / 8) / 64), dim3(256), 0, stream>>>(wq, sc, zr, wt);
  gemm_bt_kernel<<<dim3(N_DIM / 128, M_DIM / 128), dim3(256), 0, stream>>>(xb, wt, bias, out);
}

// Round 5
// 285.316 us; speedup vs baseline: 1.1618x; 1.0109x over previous
//
#include <hip/hip_runtime.h>
#include <stdint.h>

// out[M,N] = x[M,K] @ dequant(W_q_packed)[K,N] + bias[N]
// M=N=K=4096, 4-bit nibbles packed 8/int32 along K, GROUP=128.
// R5: (a) fuse cvt_x + dequant into one kernel (concurrent memory-bound
// slices, 16B cvt stores) to test the ~110us non-gemm mystery;
// (b) XCD-aware block swizzle in gemm: each XCD owns 4 contiguous B-panels
// (= 4MB = its L2) for the whole kernel -> staging latency drops.

#define M_DIM 4096
#define N_DIM 4096
#define K_DIM 4096

typedef __attribute__((ext_vector_type(8))) short short8;
typedef __attribute__((ext_vector_type(4))) float f32x4;

__device__ __forceinline__ unsigned short f2bf(float f) {
  uint32_t u = __builtin_bit_cast(uint32_t, f);
  u += 0x7fffu + ((u >> 16) & 1u);   // round-to-nearest-even
  return (unsigned short)(u >> 16);
}

// ---------- kernel 1: fused prep ----------
// blocks [0,2048): x fp32 -> bf16 (ushort8 stores).
// blocks [2048,3072): dequant + transpose -> W^T (N x K) bf16.
__global__ __launch_bounds__(256) void prep_kernel(const float* __restrict__ x,
                                                   unsigned short* __restrict__ xb,
                                                   const int* __restrict__ Wq,
                                                   const float* __restrict__ scales,
                                                   const float* __restrict__ zeros,
                                                   unsigned short* __restrict__ wt) {
  __shared__ uint4 Ts[32 * 64];  // 32 KB (dequant slice only)
  const int tid = threadIdx.x;
  if (blockIdx.x < 2048) {
    const int total = (M_DIM * K_DIM) / 8;   // 2M ushort8
    const float4* x4 = (const float4*)x;
    uint4* o8 = (uint4*)xb;
#pragma unroll
    for (int p = 0; p < 4; ++p) {
      int i = (p * 2048 + blockIdx.x) * 256 + tid;
      if (i < total) {
        float4 a = x4[2 * i], b = x4[2 * i + 1];
        uint4 o;
        o.x = (uint32_t)f2bf(a.x) | ((uint32_t)f2bf(a.y) << 16);
        o.y = (uint32_t)f2bf(a.z) | ((uint32_t)f2bf(a.w) << 16);
        o.z = (uint32_t)f2bf(b.x) | ((uint32_t)f2bf(b.y) << 16);
        o.w = (uint32_t)f2bf(b.z) | ((uint32_t)f2bf(b.w) << 16);
        o8[i] = o;
      }
    }
    return;
  }
  const int blk = blockIdx.x - 2048;
  const int n0 = (blk & 127) * 32;        // N/32 = 128 tiles
  const int gk0 = (blk >> 7) * 64;        // (K/8)/64 = 8 tiles

#pragma unroll
  for (int p = 0; p < 8; ++p) {
    int e = p * 256 + tid;
    int n_l = e & 31;
    int gk_l = e >> 5;
    int gk = gk0 + gk_l;
    int n = n0 + n_l;
    int g = gk >> 4;                // group = (gk*8)/128
    uint32_t q = (uint32_t)Wq[gk * N_DIM + n];
    float s = scales[g * N_DIM + n];
    float z = zeros[g * N_DIM + n];
    unsigned short b[8];
#pragma unroll
    for (int j = 0; j < 8; ++j) {
      float f = ((float)((q >> (4 * j)) & 15u) - z) * s;
      b[j] = f2bf(f);
    }
    uint4 cell;
    cell.x = (uint32_t)b[0] | ((uint32_t)b[1] << 16);
    cell.y = (uint32_t)b[2] | ((uint32_t)b[3] << 16);
    cell.z = (uint32_t)b[4] | ((uint32_t)b[5] << 16);
    cell.w = (uint32_t)b[6] | ((uint32_t)b[7] << 16);
    Ts[n_l * 64 + (gk_l ^ (n_l & 7))] = cell;
  }
  __syncthreads();
  uint4* dst = (uint4*)wt;
#pragma unroll
  for (int p = 0; p < 8; ++p) {
    int n_l = p * 4 + (tid >> 6);
    int gk_l = tid & 63;
    uint4 cell = Ts[n_l * 64 + (gk_l ^ (n_l & 7))];
    dst[(size_t)(n0 + n_l) * (K_DIM / 8) + (gk0 + gk_l)] = cell;
  }
}

// ---------- kernel 2: bf16 GEMM, C = A @ Bt^T + bias ----------
// 128x128 tile, 4 waves 2x2, each wave 64x64 via 4x4 of 16x16x32 MFMA, BK=64.
// LDS: 16B cells, tile = 128 rows x 8 k-chunks, cell = row*8 + (kc^(row&7)).
// XCD swizzle: linear block b -> xcd=b&7 owns nt in [4*xcd, 4*xcd+4).
__global__ __launch_bounds__(256) void gemm_bt_kernel(const unsigned short* __restrict__ A,
                                                      const unsigned short* __restrict__ Bt,
                                                      const float* __restrict__ bias,
                                                      float* __restrict__ C) {
  __shared__ short8 As[1024];  // 16 KB
  __shared__ short8 Bs[1024];  // 16 KB
  const int tid = threadIdx.x;
  const int lane = tid & 63;
  const int w = tid >> 6;
  const int wm = w >> 1, wn = w & 1;

  const int b = blockIdx.x;
  const int xcd = b & 7;
  const int loc = b >> 3;              // 0..127
  const int nt = xcd * 4 + (loc & 3);  // each XCD: 4 contiguous B-panels
  const int mt = loc >> 2;             // sweeps 0..31 in XCD lockstep
  const int m0 = mt * 128;
  const int n0 = nt * 128;

  // staging: window j covers cells [w*256 + j*64, +64); lane -> cell c0 + j*64
  const int c0 = w * 256 + lane;
  const int row0 = c0 >> 3;              // rows row0 + 8j
  const int kc0 = (c0 & 7) ^ (row0 & 7); // invariant across j (row step 8)
  const unsigned short* Ablk = A + (size_t)m0 * K_DIM;
  const unsigned short* Bblk = Bt + (size_t)n0 * K_DIM;
  const int voff = row0 * K_DIM + kc0 * 8;   // varying elem offset, +8*K per j

  f32x4 acc[4][4] = {};

  const int fr = lane & 15;   // m (A) / n (B) within 16-tile
  const int fc = lane >> 4;   // k-quarter 0..3
  const int a_row8 = (wm * 64 + fr) * 8;
  const int b_row8 = (wn * 64 + fr) * 8;
  const int kx0 = fc ^ (fr & 7);          // k-step 0
  const int kx1 = (4 + fc) ^ (fr & 7);    // k-step 1

  for (int kk = 0; kk < K_DIM / 64; ++kk) {
    const int k0 = kk * 64;
    __syncthreads();
#pragma unroll
    for (int j = 0; j < 4; ++j) {
      __builtin_amdgcn_global_load_lds(
          (const __attribute__((address_space(1))) void*)(Ablk + voff + j * 8 * K_DIM + k0),
          (__attribute__((address_space(3))) void*)&As[c0 + j * 64], 16, 0, 0);
      __builtin_amdgcn_global_load_lds(
          (const __attribute__((address_space(1))) void*)(Bblk + voff + j * 8 * K_DIM + k0),
          (__attribute__((address_space(3))) void*)&Bs[c0 + j * 64], 16, 0, 0);
    }
    __syncthreads();

    {
      short8 af[4], bv[4];
#pragma unroll
      for (int mi = 0; mi < 4; ++mi) af[mi] = As[a_row8 + mi * 128 + kx0];
#pragma unroll
      for (int ni = 0; ni < 4; ++ni) bv[ni] = Bs[b_row8 + ni * 128 + kx0];
#pragma unroll
      for (int mi = 0; mi < 4; ++mi)
#pragma unroll
        for (int ni = 0; ni < 4; ++ni)
          acc[mi][ni] = __builtin_amdgcn_mfma_f32_16x16x32_bf16(af[mi], bv[ni], acc[mi][ni], 0, 0, 0);
    }
    {
      short8 af[4], bv[4];
#pragma unroll
      for (int mi = 0; mi < 4; ++mi) af[mi] = As[a_row8 + mi * 128 + kx1];
#pragma unroll
      for (int ni = 0; ni < 4; ++ni) bv[ni] = Bs[b_row8 + ni * 128 + kx1];
#pragma unroll
      for (int mi = 0; mi < 4; ++mi)
#pragma unroll
        for (int ni = 0; ni < 4; ++ni)
          acc[mi][ni] = __builtin_amdgcn_mfma_f32_16x16x32_bf16(af[mi], bv[ni], acc[mi][ni], 0, 0, 0);
    }
  }

  // epilogue: C/D layout col=lane&15, row=(lane>>4)*4+reg
  const int rr = (lane >> 4) * 4;
#pragma unroll
  for (int ni = 0; ni < 4; ++ni) {
    const int gn = n0 + wn * 64 + ni * 16 + fr;
    const float bvv = bias[gn];
#pragma unroll
    for (int mi = 0; mi < 4; ++mi) {
      const int gm = m0 + wm * 64 + mi * 16 + rr;
#pragma unroll
      for (int r = 0; r < 4; ++r)
        C[(size_t)(gm + r) * N_DIM + gn] = acc[mi][ni][r] + bvv;
    }
  }
}

extern "C" void kernel_launch(void* const* d_in, const int* in_sizes, int n_in,
                              void* d_out, int out_size, void* d_ws, size_t ws_size,
                              hipStream_t stream) {
  const float* x = (const float*)d_in[0];
  const int* wq = (const int*)d_in[1];
  const float* sc = (const float*)d_in[2];
  const float* zr = (const float*)d_in[3];
  const float* bias = (const float*)d_in[4];
  float* out = (float*)d_out;

  unsigned short* xb = (unsigned short*)d_ws;
  unsigned short* wt = (unsigned short*)((char*)d_ws + (size_t)M_DIM * K_DIM * 2);

  prep_kernel<<<dim3(3072), dim3(256), 0, stream>>>(x, xb, wq, sc, zr, wt);
  gemm_bt_kernel<<<dim3(1024), dim3(256), 0, stream>>>(xb, wt, bias, out);
}